// Round 6
// baseline (1530.854 us; speedup 1.0000x reference)
//
#include <hip/hip_runtime.h>

// Problem constants
#define NROWS 32768   // B*H*W = 32*32*32
#define CDIM  256
#define KCODES 8192
#define HWPB  1024    // H*W per batch
#define OUT_ELEMS 8388608   // 32*256*32*32
// d_out layout: [0, 8388608) = out BCHW, [8388608] = loss, [8388609, +32768) = indices (as float)

typedef unsigned short ushort_t;
typedef unsigned int uint_t;
typedef __attribute__((ext_vector_type(8))) __bf16 bf16x8;
typedef __attribute__((ext_vector_type(4))) float f32x4;
typedef __attribute__((ext_vector_type(8))) ushort_t us8;
typedef __attribute__((ext_vector_type(4))) ushort_t us4;

#define RESCORE_THRESH 3.0e-4f

// RTNE float->bf16 bits (inputs finite)
__device__ __forceinline__ ushort_t f2bf(float f) {
  uint_t u = __float_as_uint(f);
  return (ushort_t)((u + 0x7fffu + ((u >> 16) & 1u)) >> 16);
}
__device__ __forceinline__ float bf2f(ushort_t s) {
  return __uint_as_float(((uint_t)s) << 16);
}

// ---------------- inv-norm of codebook rows (fallback path) ----------------
__global__ __launch_bounds__(256) void vq_invnorm_kernel(
    const float* __restrict__ e, float* __restrict__ invn) {
  const int row  = blockIdx.x * 4 + (threadIdx.x >> 6);
  const int lane = threadIdx.x & 63;
  const float4 v = *reinterpret_cast<const float4*>(e + (size_t)row * CDIM + lane * 4);
  float s = v.x * v.x + v.y * v.y + v.z * v.z + v.w * v.w;
  #pragma unroll
  for (int o = 32; o > 0; o >>= 1) s += __shfl_down(s, o);
  if (lane == 0) invn[row] = 1.0f / fmaxf(sqrtf(s), 1e-12f);
}

// ---------------- prep B + invnorm: e fp32 -> B2 bf16 [8192][512] = [e_hi|e_lo] ----------------
__global__ __launch_bounds__(256) void vq_prep_b_kernel(
    const float* __restrict__ e, ushort_t* __restrict__ B2,
    float* __restrict__ invn) {
  const int k  = blockIdx.x * 4 + (threadIdx.x >> 6);
  const int ln = threadIdx.x & 63;
  const float4 v = reinterpret_cast<const float4*>(e + (size_t)k * CDIM)[ln];
  us4 hi, lo;
  const float vv[4] = {v.x, v.y, v.z, v.w};
  float s = 0.f;
  #pragma unroll
  for (int i = 0; i < 4; ++i) {
    ushort_t h = f2bf(vv[i]);
    hi[i] = h;
    lo[i] = f2bf(vv[i] - bf2f(h));
    s += vv[i] * vv[i];
  }
  *reinterpret_cast<us4*>(B2 + (size_t)k * 512 + ln * 4)       = hi;
  *reinterpret_cast<us4*>(B2 + (size_t)k * 512 + 256 + ln * 4) = lo;
  #pragma unroll
  for (int o = 32; o > 0; o >>= 1) s += __shfl_down(s, o);
  if (ln == 0) invn[k] = 1.0f / fmaxf(sqrtf(s), 1e-12f);
}

// ---------------- prep A: z BCHW fp32 -> A2f fragment-major bf16 ----------------
// A2f layout: 2048 row16-blocks x 16 kc-chunks x 1024 B. Within a 1KB block:
// granule g (16B) at g*16 holds row (g&15), k-elems (g>>4)*8..+8 of that chunk.
// kc 0..7 = z_hi cols kc*32..; kc 8..15 = z_lo cols (kc-8)*32..
__global__ __launch_bounds__(256) void vq_prep_a_kernel(
    const float* __restrict__ z, char* __restrict__ A2f) {
  __shared__ float zt[64][65];
  const int t    = threadIdx.x;
  const int bidx = blockIdx.x;              // 32 b * 4 cblk * 16 hwblk
  const int b    = bidx >> 6;
  const int cblk = (bidx & 63) >> 4;
  const int hwb  = bidx & 15;
  const int c0   = cblk * 64;
  const int hw0  = hwb * 64;
  #pragma unroll
  for (int rep = 0; rep < 16; ++rep) {
    const int idx = rep * 256 + t;
    const int cc = idx >> 6, hh = idx & 63;
    zt[cc][hh] = z[(size_t)(b * 256 + c0 + cc) * 1024 + hw0 + hh];
  }
  __syncthreads();
  const int q = t >> 6, r = t & 63;          // q: c-quarter, r: row within tile
  const int n   = b * 1024 + hw0 + r;
  const int R16 = n >> 4, l15 = n & 15;
  const int cb  = c0 + q * 16;               // 16 consecutive c's
  const int kc  = cb >> 5;                   // hi chunk (0..7)
  const int kg0 = (cb >> 3) & 3;             // first granule col-chunk
  us8 hi0, hi1, lo0, lo1;
  #pragma unroll
  for (int m2 = 0; m2 < 16; ++m2) {
    const float v = zt[q * 16 + m2][r];
    const ushort_t h = f2bf(v);
    const ushort_t l = f2bf(v - bf2f(h));
    if (m2 < 8) { hi0[m2] = h; lo0[m2] = l; } else { hi1[m2 - 8] = h; lo1[m2 - 8] = l; }
  }
  const size_t base = (size_t)(R16 * 16 + kc) * 1024 + (size_t)(((kg0) << 4) | l15) * 16;
  *reinterpret_cast<us8*>(A2f + base)              = hi0;
  *reinterpret_cast<us8*>(A2f + base + 256)        = hi1;   // kg0+1
  *reinterpret_cast<us8*>(A2f + base + 8192)       = lo0;   // kc+8
  *reinterpret_cast<us8*>(A2f + base + 8192 + 256) = lo1;
}

// ---------------- MFMA GEMM + top-2 argmax (barrier-free K-loop) ----------------
// Block: 256 rows x 256 codes, 8 waves (wr=w>>2, wc=w&3), wave tile 128x64.
// A fragments loaded DIRECT from global (fragment-major A2f, coalesced 1KB/wave).
// B: per-wave private LDS slice (64 codes x 32 K = 4KB), 4-deep buffer rotation,
// inverse-swizzled global source + swizzled ds_read -> no conflicts, no barriers.
// Virtual K = 768 (24 tiles of 32): kc 0..7 zh*eh, 8..15 zl*eh, 16..23 zh*el.
__global__ __launch_bounds__(512) void vq_mfma_kernel(
    const char* __restrict__ A2f, const ushort_t* __restrict__ B2,
    const float* __restrict__ invn,
    float* __restrict__ partV1, int* __restrict__ partI1,
    float* __restrict__ partV2) {
  extern __shared__ char smem[];   // [4 bufs][8 waves][4KB] = 131072, cand at +131072

  const int t = threadIdx.x;
  const int w = t >> 6, l = t & 63;
  const int wr = w >> 2, wc = w & 3;
  const int l15 = l & 15, kg = l >> 4;
  const int m0 = blockIdx.x * 256;
  const int cg = blockIdx.y;

  // B staging lane constants
  const int rowB  = l >> 2;                    // row within 16-row group
  const int slotB = (l & 3) ^ ((l >> 2) & 3);  // inverse-swizzled source slot
  // B ds_read lane constant (slot = kg ^ (row&3), row&3 == l15&3)
  const int rdoffB = l15 * 64 + ((kg ^ (l15 & 3)) << 4);
  // A fragment base (direct global): af[i] at + i*16384 + kcA*1024
  const char* aFbase = A2f + (size_t)m0 * 1024 + (size_t)wr * 131072 + (size_t)l * 16;

  float* candV1 = reinterpret_cast<float*>(smem + 131072);
  int*   candI1 = reinterpret_cast<int*>(smem + 135168);
  float* candV2 = reinterpret_cast<float*>(smem + 139264);

  auto stageB = [&](int s3) {
    if (s3 >= 96) return;
    const int nt3 = s3 / 24;
    const int kc3 = s3 - nt3 * 24;
    const int boff = (kc3 < 8) ? kc3 * 32
                   : (kc3 < 16 ? (kc3 - 8) * 32 : 256 + (kc3 - 16) * 32);
    const int bufb = (s3 & 3) * 32768 + w * 4096;
    const ushort_t* src = B2 +
        (size_t)((cg << 10) + nt3 * 256 + wc * 64 + rowB) * 512 + slotB * 8 + boff;
    #pragma unroll
    for (int u = 0; u < 4; ++u) {
      __builtin_amdgcn_global_load_lds(
          (const __attribute__((address_space(1))) void*)(src + (size_t)u * (16 * 512)),
          (__attribute__((address_space(3))) void*)(smem + bufb + u * 1024 + l * 16),
          16, 0, 0);
    }
  };

  // prologue: prefetch first 3 tiles
  stageB(0); stageB(1); stageB(2);

  float rv1 = -3.4e38f, rv2 = -3.4e38f; int ri1 = 0;   // running top-2 (t<256: row t)

  for (int nt = 0; nt < 4; ++nt) {
    const int nbase = (cg << 10) + nt * 256;
    f32x4 acc[8][4];
    #pragma unroll
    for (int i = 0; i < 8; ++i)
      #pragma unroll
      for (int j = 0; j < 4; ++j) acc[i][j] = (f32x4){0.f, 0.f, 0.f, 0.f};

    for (int kc = 0; kc < 24; ++kc) {
      const int s = nt * 24 + kc;
      stageB(s + 3);
      // belt-and-braces: everything older than the newest 8 VMEM ops (the two
      // most recent stage batches) is complete -> buf[s&3] ready. No stall in
      // steady state (older loads are already drained by af-use waits).
      asm volatile("s_waitcnt vmcnt(8)" ::: "memory");

      const int kcA = (kc < 16) ? kc : kc - 16;
      const char* aa = aFbase + (size_t)kcA * 1024;
      bf16x8 af[8];
      #pragma unroll
      for (int i = 0; i < 8; ++i)
        af[i] = *reinterpret_cast<const bf16x8*>(aa + (size_t)i * 16384);

      const char* bb = smem + (s & 3) * 32768 + w * 4096 + rdoffB;
      bf16x8 bfr[4];
      #pragma unroll
      for (int j = 0; j < 4; ++j)
        bfr[j] = *reinterpret_cast<const bf16x8*>(bb + j * 1024);

      __builtin_amdgcn_s_setprio(1);
      #pragma unroll
      for (int i = 0; i < 8; ++i)
        #pragma unroll
        for (int j = 0; j < 4; ++j)
          acc[i][j] = __builtin_amdgcn_mfma_f32_16x16x32_bf16(af[i], bfr[j], acc[i][j], 0, 0, 0);
      __builtin_amdgcn_s_setprio(0);
    }

    // ---- per-nt epilogue: top-2 over this 256-code tile ----
    float inv[4];
    #pragma unroll
    for (int j = 0; j < 4; ++j) inv[j] = invn[nbase + wc * 64 + j * 16 + l15];

    #pragma unroll
    for (int i = 0; i < 8; ++i) {
      #pragma unroll
      for (int q = 0; q < 4; ++q) {
        // fold j (cols ascending -> strict > keeps smallest col)
        float v1 = acc[i][0][q] * inv[0];
        int   i1 = nbase + wc * 64 + l15;
        float v2 = -3.4e38f;
        #pragma unroll
        for (int j = 1; j < 4; ++j) {
          const float v = acc[i][j][q] * inv[j];
          const int   c = nbase + wc * 64 + j * 16 + l15;
          if (v > v1) { v2 = v1; v1 = v; i1 = c; }
          else if (v > v2) v2 = v;
        }
        // butterfly across the 16 lanes of this row group
        #pragma unroll
        for (int m = 1; m < 16; m <<= 1) {
          const float ov = __shfl_xor(v1, m);
          const int   oi = __shfl_xor(i1, m);
          const float o2 = __shfl_xor(v2, m);
          const float n2 = fmaxf(fmaxf(v2, o2), fminf(v1, ov));
          if (ov > v1 || (ov == v1 && oi < i1)) { v1 = ov; i1 = oi; }
          v2 = n2;
        }
        if (l15 == 0) {
          const int row = wr * 128 + i * 16 + kg * 4 + q;
          candV1[wc * 256 + row] = v1;
          candI1[wc * 256 + row] = i1;
          candV2[wc * 256 + row] = v2;
        }
      }
    }
    asm volatile("s_waitcnt lgkmcnt(0)" ::: "memory");
    __builtin_amdgcn_s_barrier();
    if (t < 256) {
      #pragma unroll
      for (int wcc = 0; wcc < 4; ++wcc) {
        const float v1c = candV1[wcc * 256 + t];
        const int   i1c = candI1[wcc * 256 + t];
        const float v2c = candV2[wcc * 256 + t];
        const float n2 = fmaxf(fmaxf(rv2, v2c), fminf(rv1, v1c));
        if (v1c > rv1 || (v1c == rv1 && i1c < ri1)) { rv1 = v1c; ri1 = i1c; }
        rv2 = n2;
      }
    }
    __builtin_amdgcn_s_barrier();
  }

  if (t < 256) {
    const size_t g = (size_t)cg * NROWS + m0 + t;
    partV1[g] = rv1; partI1[g] = ri1; partV2[g] = rv2;
  }
}

// ---------------- merge colgroups, flag low-margin rows ----------------
__global__ __launch_bounds__(256) void vq_merge_flag_kernel(
    const float* __restrict__ partV1, const int* __restrict__ partI1,
    const float* __restrict__ partV2,
    int* __restrict__ final_idx, int* __restrict__ flag, int* __restrict__ cnt) {
  const int n = blockIdx.x * 256 + threadIdx.x;
  float v1 = partV1[n]; int i1 = partI1[n]; float v2 = partV2[n];
  #pragma unroll
  for (int cg = 1; cg < 8; ++cg) {
    const float pv1 = partV1[(size_t)cg * NROWS + n];
    const int   pi1 = partI1[(size_t)cg * NROWS + n];
    const float pv2 = partV2[(size_t)cg * NROWS + n];
    const float n2 = fmaxf(fmaxf(v2, pv2), fminf(v1, pv1));
    if (pv1 > v1) { v1 = pv1; i1 = pi1; }   // ties keep earlier cg (smaller k)
    v2 = n2;
  }
  final_idx[n] = i1;
  if (v1 - v2 < RESCORE_THRESH) {
    const int p = atomicAdd(cnt, 1);
    flag[p] = n;
  }
}

// ---------------- exact fp32 rescore of flagged rows ----------------
__global__ __launch_bounds__(256) void vq_rescore_kernel(
    const float* __restrict__ z, const float* __restrict__ e,
    const float* __restrict__ invn, const int* __restrict__ cnt,
    const int* __restrict__ flag, int* __restrict__ final_idx) {
  __shared__ float zr[8][256];
  __shared__ int rows[8];
  __shared__ float redv[8][4];
  __shared__ int   redi[8][4];
  const int t = threadIdx.x;
  const int total = *cnt;
  for (int base = blockIdx.x * 8; base < total; base += gridDim.x * 8) {
    const int nr = min(8, total - base);
    __syncthreads();
    if (t < 8) rows[t] = (base + t < total) ? flag[base + t] : flag[base];
    __syncthreads();
    for (int rr = 0; rr < 8; ++rr) {
      if (rr < nr) {
        const int n = rows[rr];
        const int b = n >> 10, hw = n & 1023;
        zr[rr][t] = z[(size_t)b * 262144 + (size_t)t * 1024 + hw];
      } else {
        zr[rr][t] = 0.f;
      }
    }
    __syncthreads();
    float bvv[8]; int bii[8];
    #pragma unroll
    for (int rr = 0; rr < 8; ++rr) { bvv[rr] = -3.4e38f; bii[rr] = 0; }
    for (int jj = 0; jj < 32; ++jj) {
      const int k = t * 32 + jj;
      const float4* er = reinterpret_cast<const float4*>(e + (size_t)k * CDIM);
      float d[8];
      #pragma unroll
      for (int rr = 0; rr < 8; ++rr) d[rr] = 0.f;
      for (int c4 = 0; c4 < 64; ++c4) {
        const float4 ev = er[c4];
        #pragma unroll
        for (int rr = 0; rr < 8; ++rr) {
          d[rr] = fmaf(ev.x, zr[rr][c4 * 4 + 0], d[rr]);
          d[rr] = fmaf(ev.y, zr[rr][c4 * 4 + 1], d[rr]);
          d[rr] = fmaf(ev.z, zr[rr][c4 * 4 + 2], d[rr]);
          d[rr] = fmaf(ev.w, zr[rr][c4 * 4 + 3], d[rr]);
        }
      }
      const float inv = invn[k];
      #pragma unroll
      for (int rr = 0; rr < 8; ++rr) {
        const float v = d[rr] * inv;
        if (v > bvv[rr]) { bvv[rr] = v; bii[rr] = k; }  // ascending k: first kept
      }
    }
    #pragma unroll
    for (int m = 1; m < 64; m <<= 1) {
      #pragma unroll
      for (int rr = 0; rr < 8; ++rr) {
        const float ov = __shfl_xor(bvv[rr], m);
        const int   oi = __shfl_xor(bii[rr], m);
        if (ov > bvv[rr] || (ov == bvv[rr] && oi < bii[rr])) { bvv[rr] = ov; bii[rr] = oi; }
      }
    }
    if ((t & 63) == 0) {
      #pragma unroll
      for (int rr = 0; rr < 8; ++rr) { redv[rr][t >> 6] = bvv[rr]; redi[rr][t >> 6] = bii[rr]; }
    }
    __syncthreads();
    if (t < nr) {
      float v = redv[t][0]; int i = redi[t][0];
      #pragma unroll
      for (int ww = 1; ww < 4; ++ww) {
        if (redv[t][ww] > v || (redv[t][ww] == v && redi[t][ww] < i)) { v = redv[t][ww]; i = redi[t][ww]; }
      }
      final_idx[rows[t]] = i;
    }
  }
}

// ---------------- gather + out + loss: streaming, 1 thread per row ----------------
__global__ __launch_bounds__(256) void vq_gather_loss3_kernel(
    const float* __restrict__ z, const float* __restrict__ e,
    const int* __restrict__ final_idx,
    float* __restrict__ out, float* __restrict__ lossacc) {
  const int t = threadIdx.x;
  const int n = blockIdx.x * 256 + t;        // all 256 rows share batch b
  const int b = n >> 10, hw = n & 1023;
  const int id = final_idx[n];
  out[OUT_ELEMS + 1 + n] = (float)id;
  const float4* er = reinterpret_cast<const float4*>(e + (size_t)id * CDIM);
  const size_t zb = (size_t)b * 262144 + hw;
  float lsum = 0.f;
  for (int c4 = 0; c4 < 64; ++c4) {
    const float4 ev = er[c4];
    const float evv[4] = {ev.x, ev.y, ev.z, ev.w};
    #pragma unroll
    for (int u = 0; u < 4; ++u) {
      const size_t off = zb + (size_t)(c4 * 4 + u) * 1024;
      const float d = evv[u] - z[off];
      lsum += d * d;
      out[off] = evv[u];
    }
  }
  #pragma unroll
  for (int o = 32; o > 0; o >>= 1) lsum += __shfl_down(lsum, o);
  __shared__ float wsum[4];
  if ((t & 63) == 0) wsum[t >> 6] = lsum;
  __syncthreads();
  if (t == 0) atomicAdd(lossacc, wsum[0] + wsum[1] + wsum[2] + wsum[3]);
}

__global__ void vq_finalize_kernel(const float* __restrict__ lossacc,
                                   float* __restrict__ out) {
  out[OUT_ELEMS] = 1.25f * lossacc[0] / (float)OUT_ELEMS;
}

// ================= fallback fp32 path (round-3, proven) =================
#define BM 128
#define BN 128
#define KC 16
#define KSPLIT 4

__global__ __launch_bounds__(256) void vq_dist_argmax_kernel(
    const float* __restrict__ z, const float* __restrict__ e,
    const float* __restrict__ invn,
    float* __restrict__ bestval, int* __restrict__ bestidx) {
  __shared__ float as[KC][BM];
  __shared__ float bs[KC][BN + 4];
  const int t  = threadIdx.x;
  const int tx = t & 15;
  const int ty = t >> 4;
  const int n0 = blockIdx.x * BM;
  const int b   = n0 >> 10;
  const int hw0 = n0 & 1023;
  const float* zbase = z + (size_t)b * (CDIM * HWPB) + hw0;
  const int kbeg = blockIdx.y * (KCODES / KSPLIT);
  float bv[8]; int bi[8];
  #pragma unroll
  for (int i = 0; i < 8; ++i) { bv[i] = -3.4e38f; bi[i] = 0; }
  const int a_lm4 = (t & 31) * 4;
  const int a_cc  = t >> 5;
  const int b_kk  = t >> 2;
  const int b_q4  = (t & 3) * 4;
  for (int kt = 0; kt < (KCODES / KSPLIT) / BN; ++kt) {
    const int k0 = kbeg + kt * BN;
    float acc[8][8];
    #pragma unroll
    for (int i = 0; i < 8; ++i)
      #pragma unroll
      for (int j = 0; j < 8; ++j) acc[i][j] = 0.f;
    for (int c0 = 0; c0 < CDIM; c0 += KC) {
      #pragma unroll
      for (int p = 0; p < 2; ++p) {
        const int cc = a_cc + 8 * p;
        const float4 v = *reinterpret_cast<const float4*>(
            zbase + (size_t)(c0 + cc) * HWPB + a_lm4);
        *reinterpret_cast<float4*>(&as[cc][a_lm4]) = v;
      }
      #pragma unroll
      for (int p = 0; p < 2; ++p) {
        const int kk = b_kk + 64 * p;
        const float4 v = *reinterpret_cast<const float4*>(
            e + (size_t)(k0 + kk) * CDIM + c0 + b_q4);
        bs[b_q4 + 0][kk] = v.x;
        bs[b_q4 + 1][kk] = v.y;
        bs[b_q4 + 2][kk] = v.z;
        bs[b_q4 + 3][kk] = v.w;
      }
      __syncthreads();
      #pragma unroll
      for (int cc = 0; cc < KC; ++cc) {
        const float4 a0 = *reinterpret_cast<const float4*>(&as[cc][ty * 8]);
        const float4 a1 = *reinterpret_cast<const float4*>(&as[cc][ty * 8 + 4]);
        const float4 b0 = *reinterpret_cast<const float4*>(&bs[cc][tx * 4]);
        const float4 b1 = *reinterpret_cast<const float4*>(&bs[cc][64 + tx * 4]);
        const float a[8]  = {a0.x, a0.y, a0.z, a0.w, a1.x, a1.y, a1.z, a1.w};
        const float bb[8] = {b0.x, b0.y, b0.z, b0.w, b1.x, b1.y, b1.z, b1.w};
        #pragma unroll
        for (int i = 0; i < 8; ++i)
          #pragma unroll
          for (int j = 0; j < 8; ++j)
            acc[i][j] = fmaf(a[i], bb[j], acc[i][j]);
      }
      __syncthreads();
    }
    #pragma unroll
    for (int j = 0; j < 8; ++j) {
      const int k = k0 + ((j < 4) ? (tx * 4 + j) : (64 + tx * 4 + (j - 4)));
      const float inv = invn[k];
      #pragma unroll
      for (int i = 0; i < 8; ++i) {
        const float v = acc[i][j] * inv;
        if (v > bv[i]) { bv[i] = v; bi[i] = k; }
      }
    }
  }
  #pragma unroll
  for (int m = 1; m < 16; m <<= 1) {
    #pragma unroll
    for (int i = 0; i < 8; ++i) {
      const float vo = __shfl_xor(bv[i], m);
      const int   io = __shfl_xor(bi[i], m);
      if (vo > bv[i] || (vo == bv[i] && io < bi[i])) { bv[i] = vo; bi[i] = io; }
    }
  }
  if (tx == 0) {
    #pragma unroll
    for (int i = 0; i < 8; ++i) {
      bestval[blockIdx.y * NROWS + n0 + ty * 8 + i] = bv[i];
      bestidx[blockIdx.y * NROWS + n0 + ty * 8 + i] = bi[i];
    }
  }
}

__global__ __launch_bounds__(256) void vq_gather_loss_kernel(
    const float* __restrict__ z, const float* __restrict__ e,
    const float* __restrict__ bestval, const int* __restrict__ bestidx,
    float* __restrict__ out, float* __restrict__ lossacc) {
  __shared__ int sidx[64];
  const int t  = threadIdx.x;
  const int n0 = blockIdx.x * 64;
  if (t < 64) {
    const int n = n0 + t;
    float best = bestval[n];
    int   bid  = bestidx[n];
    #pragma unroll
    for (int p = 1; p < KSPLIT; ++p) {
      const float v = bestval[p * NROWS + n];
      const int  id = bestidx[p * NROWS + n];
      if (v > best) { best = v; bid = id; }
    }
    sidx[t] = bid;
    out[OUT_ELEMS + 1 + n] = (float)bid;
  }
  __syncthreads();
  const int b    = n0 >> 10;
  const int hw0  = n0 & 1023;
  const int nsub = t & 63;
  const int cg   = t >> 6;
  const float* erow = e + (size_t)sidx[nsub] * CDIM;
  float lsum = 0.f;
  for (int c = cg; c < CDIM; c += 4) {
    const float  v   = erow[c];
    const size_t off = (size_t)b * (CDIM * HWPB) + (size_t)c * HWPB + hw0 + nsub;
    const float  d   = v - z[off];
    lsum += d * d;
    out[off] = v;
  }
  #pragma unroll
  for (int o = 32; o > 0; o >>= 1) lsum += __shfl_down(lsum, o);
  __shared__ float wsum[4];
  if ((t & 63) == 0) wsum[t >> 6] = lsum;
  __syncthreads();
  if (t == 0) atomicAdd(lossacc, wsum[0] + wsum[1] + wsum[2] + wsum[3]);
}

// ================================ launch ================================
extern "C" void kernel_launch(void* const* d_in, const int* in_sizes, int n_in,
                              void* d_out, int out_size, void* d_ws, size_t ws_size,
                              hipStream_t stream) {
  const float* z = (const float*)d_in[0];        // [32,256,32,32]
  const float* e = (const float*)d_in[1];        // [8192,256]
  float* out = (float*)d_out;

  const size_t szA2 = (size_t)2048 * 16 * 1024;      // 33,554,432 (A2f)
  const size_t szB2 = (size_t)KCODES * 512 * 2;      //  8,388,608
  const size_t szInv = KCODES * 4;
  const size_t szPart = (size_t)8 * NROWS * 4;
  const size_t need = szA2 + szB2 + szInv + 3 * szPart + 2 * (size_t)NROWS * 4 + 256;

  if (ws_size >= need) {
    char* p = (char*)d_ws;
    char* A2f = p;                     p += szA2;
    ushort_t* B2 = (ushort_t*)p;       p += szB2;
    float* invn  = (float*)p;          p += szInv;
    float* partV1 = (float*)p;         p += szPart;
    float* partV2 = (float*)p;         p += szPart;
    int*   partI1 = (int*)p;           p += szPart;
    int*   final_idx = (int*)p;        p += (size_t)NROWS * 4;
    int*   flag = (int*)p;             p += (size_t)NROWS * 4;
    int*   cnt = (int*)p;
    float* lossacc = (float*)(cnt + 1);

    hipMemsetAsync(cnt, 0, 8, stream);  // cnt + lossacc
    vq_prep_b_kernel<<<KCODES / 4, 256, 0, stream>>>(e, B2, invn);
    vq_prep_a_kernel<<<2048, 256, 0, stream>>>(z, A2f);
    dim3 grid(NROWS / 256, 8);
    vq_mfma_kernel<<<grid, 512, 143360, stream>>>(A2f, B2, invn, partV1, partI1, partV2);
    vq_merge_flag_kernel<<<NROWS / 256, 256, 0, stream>>>(partV1, partI1, partV2,
                                                          final_idx, flag, cnt);
    vq_rescore_kernel<<<256, 256, 0, stream>>>(z, e, invn, cnt, flag, final_idx);
    vq_gather_loss3_kernel<<<NROWS / 256, 256, 0, stream>>>(z, e, final_idx, out, lossacc);
    vq_finalize_kernel<<<1, 1, 0, stream>>>(lossacc, out);
  } else {
    // fallback: proven fp32 path (round 3)
    float* invn    = (float*)d_ws;
    float* bestval = invn + KCODES;
    int*   bestidx = (int*)(bestval + KSPLIT * NROWS);
    float* lossacc = (float*)(bestidx + KSPLIT * NROWS);
    hipMemsetAsync(lossacc, 0, sizeof(float), stream);
    vq_invnorm_kernel<<<KCODES / 4, 256, 0, stream>>>(e, invn);
    dim3 grid(NROWS / BM, KSPLIT);
    vq_dist_argmax_kernel<<<grid, 256, 0, stream>>>(z, e, invn, bestval, bestidx);
    vq_gather_loss_kernel<<<NROWS / 64, 256, 0, stream>>>(z, e, bestval, bestidx,
                                                          out, lossacc);
    vq_finalize_kernel<<<1, 1, 0, stream>>>(lossacc, out);
  }
}

// Round 9
// 1347.343 us; speedup vs baseline: 1.1362x; 1.1362x over previous
//
#include <hip/hip_runtime.h>

// Problem constants
#define NROWS 32768   // B*H*W = 32*32*32
#define CDIM  256
#define KCODES 8192
#define HWPB  1024    // H*W per batch
#define OUT_ELEMS 8388608   // 32*256*32*32
// d_out layout: [0, 8388608) = out BCHW, [8388608] = loss, [8388609, +32768) = indices (as float)

typedef unsigned short ushort_t;
typedef unsigned int uint_t;
typedef __attribute__((ext_vector_type(8))) __bf16 bf16x8;
typedef __attribute__((ext_vector_type(4))) float f32x4;
typedef __attribute__((ext_vector_type(8))) ushort_t us8;
typedef __attribute__((ext_vector_type(4))) ushort_t us4;

// 3-product split: z_hi*e_hi + z_lo*e_hi + z_hi*e_lo. Dropped z_lo*e_lo +
// bf16-residuals give dist error sigma ~1e-5; 3e-4 threshold = many sigma.
// (Round-7 lesson: single-bf16 codebook has sigma ~1.1e-3 -- NOT viable.)
#define RESCORE_THRESH 3.0e-4f

// RTNE float->bf16 bits (inputs finite)
__device__ __forceinline__ ushort_t f2bf(float f) {
  uint_t u = __float_as_uint(f);
  return (ushort_t)((u + 0x7fffu + ((u >> 16) & 1u)) >> 16);
}
__device__ __forceinline__ float bf2f(ushort_t s) {
  return __uint_as_float(((uint_t)s) << 16);
}

// ---------------- inv-norm of codebook rows (fallback path) ----------------
__global__ __launch_bounds__(256) void vq_invnorm_kernel(
    const float* __restrict__ e, float* __restrict__ invn) {
  const int row  = blockIdx.x * 4 + (threadIdx.x >> 6);
  const int lane = threadIdx.x & 63;
  const float4 v = *reinterpret_cast<const float4*>(e + (size_t)row * CDIM + lane * 4);
  float s = v.x * v.x + v.y * v.y + v.z * v.z + v.w * v.w;
  #pragma unroll
  for (int o = 32; o > 0; o >>= 1) s += __shfl_down(s, o);
  if (lane == 0) invn[row] = 1.0f / fmaxf(sqrtf(s), 1e-12f);
}

// ---------------- prep B + invnorm: e fp32 -> B2 bf16 [8192][512] = [e_hi|e_lo] ----------------
__global__ __launch_bounds__(256) void vq_prep_b_kernel(
    const float* __restrict__ e, ushort_t* __restrict__ B2,
    float* __restrict__ invn) {
  const int k  = blockIdx.x * 4 + (threadIdx.x >> 6);
  const int ln = threadIdx.x & 63;
  const float4 v = reinterpret_cast<const float4*>(e + (size_t)k * CDIM)[ln];
  us4 hi, lo;
  const float vv[4] = {v.x, v.y, v.z, v.w};
  float s = 0.f;
  #pragma unroll
  for (int i = 0; i < 4; ++i) {
    ushort_t h = f2bf(vv[i]);
    hi[i] = h;
    lo[i] = f2bf(vv[i] - bf2f(h));
    s += vv[i] * vv[i];
  }
  *reinterpret_cast<us4*>(B2 + (size_t)k * 512 + ln * 4)       = hi;
  *reinterpret_cast<us4*>(B2 + (size_t)k * 512 + 256 + ln * 4) = lo;
  #pragma unroll
  for (int o = 32; o > 0; o >>= 1) s += __shfl_down(s, o);
  if (ln == 0) invn[k] = 1.0f / fmaxf(sqrtf(s), 1e-12f);
}

// ---------------- prep A: z BCHW fp32 -> A2 bf16 [32768][512] = [z_hi | z_lo] ----------------
__global__ __launch_bounds__(256) void vq_prep_a_kernel(
    const float* __restrict__ z, ushort_t* __restrict__ A2) {
  __shared__ float zt[64][65];
  const int t    = threadIdx.x;
  const int bidx = blockIdx.x;              // 32 b * 4 cblk * 16 hwblk
  const int b    = bidx >> 6;
  const int cblk = (bidx & 63) >> 4;
  const int hwb  = bidx & 15;
  const int c0   = cblk * 64;
  const int hw0  = hwb * 64;
  #pragma unroll
  for (int rep = 0; rep < 16; ++rep) {
    const int idx = rep * 256 + t;
    const int cc = idx >> 6, hh = idx & 63;
    zt[cc][hh] = z[(size_t)(b * 256 + c0 + cc) * 1024 + hw0 + hh];
  }
  __syncthreads();
  const int r = t >> 2, q = t & 3;
  const int n = b * 1024 + hw0 + r;
  us8 hi0, hi1, lo0, lo1;
  #pragma unroll
  for (int m2 = 0; m2 < 16; ++m2) {
    const float v = zt[q * 16 + m2][r];
    const ushort_t h = f2bf(v);
    const ushort_t l = f2bf(v - bf2f(h));
    if (m2 < 8) { hi0[m2] = h; lo0[m2] = l; } else { hi1[m2 - 8] = h; lo1[m2 - 8] = l; }
  }
  ushort_t* hrow = A2 + (size_t)n * 512 + c0 + q * 16;
  ushort_t* lrow = A2 + (size_t)n * 512 + 256 + c0 + q * 16;
  *reinterpret_cast<us8*>(hrow)     = hi0;
  *reinterpret_cast<us8*>(hrow + 8) = hi1;
  *reinterpret_cast<us8*>(lrow)     = lo0;
  *reinterpret_cast<us8*>(lrow + 8) = lo1;
}

// ---------------- MFMA GEMM + top-2 argmax (counted-vmcnt double buffer) ----------------
// K=768 virtual (12 kc of 64): kc 0-3 z_hi*e_hi, 4-7 z_lo*e_hi, 8-11 z_hi*e_lo.
// 96 linear steps (8 nt x 12 kc), 2 LDS buffers, 2 tiles in flight. Per step:
//   s_waitcnt vmcnt(8)  (tile s done; tile s+1's 8 loads stay in flight)
//   s_barrier; sched_barrier    (cross-wave visibility; pin reads below)
//   ds_read + 32 MFMA
//   s_barrier; sched_barrier    (all waves done reading buf)
//   stage(s+2 -> buf)
// Only step 96 drains to vmcnt(0). (T3/T4; round-5 drained every step.)
__global__ __launch_bounds__(256, 2) void vq_mfma_kernel(
    const ushort_t* __restrict__ A2, const ushort_t* __restrict__ B2,
    const float* __restrict__ invn,
    float* __restrict__ partV1, int* __restrict__ partI1,
    float* __restrict__ partV2) {
  __shared__ __align__(16) char As[2][16384];
  __shared__ __align__(16) char Bs[2][16384];

  const int t = threadIdx.x;
  const int w = t >> 6, l = t & 63;
  const int wr = w >> 1, wc = w & 1;
  const int l15 = l & 15, kg = l >> 4;
  const int m0 = blockIdx.x * 128;
  const int cg = blockIdx.y;

  const int lr = l >> 3;            // staging: row within 8-row group
  const int lc = (l & 7) ^ lr;      // staging: swizzled source 16B-slot

  const ushort_t* aRow = A2 + (size_t)(m0 + w * 8 + lr) * 512 + lc * 8;
  const ushort_t* bRow = B2 + (size_t)(cg * 1024 + w * 8 + lr) * 512 + lc * 8;
  const int ldsOff = (w * 8) * 128;

  auto stage = [&](int s3, int buf) {
    const int nt3 = s3 / 12, kc3 = s3 - nt3 * 12;
    const int seg = kc3 >> 2, rem = (kc3 & 3) * 64;
    const int aoff = (seg == 1 ? 256 : 0) + rem;
    const int boff = (seg == 2 ? 256 : 0) + rem;
    const size_t bNt = (size_t)nt3 * (128 * 512);
    #pragma unroll
    for (int p = 0; p < 4; ++p) {
      __builtin_amdgcn_global_load_lds(
          (const __attribute__((address_space(1))) void*)(aRow + (size_t)p * (32 * 512) + aoff),
          (__attribute__((address_space(3))) void*)(As[buf] + p * 32 * 128 + ldsOff), 16, 0, 0);
      __builtin_amdgcn_global_load_lds(
          (const __attribute__((address_space(1))) void*)(bRow + bNt + (size_t)p * (32 * 512) + boff),
          (__attribute__((address_space(3))) void*)(Bs[buf] + p * 32 * 128 + ldsOff), 16, 0, 0);
    }
  };

  float bv[16], b2v[16]; int bi[16];
  #pragma unroll
  for (int iq = 0; iq < 16; ++iq) { bv[iq] = -3.4e38f; b2v[iq] = -3.4e38f; bi[iq] = 0; }

  // prologue: two tiles in flight
  stage(0, 0);
  stage(1, 1);

  int s = 0;
  for (int nt = 0; nt < 8; ++nt) {
    const int nbase = (cg << 10) + nt * 128;
    f32x4 acc[4][4];
    #pragma unroll
    for (int i = 0; i < 4; ++i)
      #pragma unroll
      for (int j = 0; j < 4; ++j) acc[i][j] = (f32x4){0.f, 0.f, 0.f, 0.f};

    for (int kc = 0; kc < 12; ++kc, ++s) {
      const int buf = s & 1;
      if (s < 95) {
        asm volatile("s_waitcnt vmcnt(8)" ::: "memory");   // tile s done; s+1 in flight
      } else {
        asm volatile("s_waitcnt vmcnt(0)" ::: "memory");   // final tile: drain
      }
      __builtin_amdgcn_s_barrier();
      __builtin_amdgcn_sched_barrier(0);

      const char* Ab = As[buf];
      const char* Bb = Bs[buf];
      #pragma unroll
      for (int kk = 0; kk < 2; ++kk) {
        bf16x8 af[4], bfr[4];
        const int sw = kk * 64 + kg * 16;
        const int sx = (l15 & 7) << 4;
        #pragma unroll
        for (int i = 0; i < 4; ++i)
          af[i] = *reinterpret_cast<const bf16x8*>(
              Ab + (wr * 64 + i * 16 + l15) * 128 + (sw ^ sx));
        #pragma unroll
        for (int j = 0; j < 4; ++j)
          bfr[j] = *reinterpret_cast<const bf16x8*>(
              Bb + (wc * 64 + j * 16 + l15) * 128 + (sw ^ sx));
        #pragma unroll
        for (int i = 0; i < 4; ++i)
          #pragma unroll
          for (int j = 0; j < 4; ++j)
            acc[i][j] = __builtin_amdgcn_mfma_f32_16x16x32_bf16(af[i], bfr[j], acc[i][j], 0, 0, 0);
      }

      __builtin_amdgcn_s_barrier();      // all waves done reading buf
      __builtin_amdgcn_sched_barrier(0); // pin stage below the barrier
      if (s + 2 < 96) stage(s + 2, buf); // overwrite buf with tile s+2
    }

    // per-nt epilogue: scale by invn, running top-2 per owned row.
    // (The 4 invn loads add to the vmcnt stream, but any later vmcnt(8) wait
    // still drains them before older stage batches -- counting stays safe.)
    float inv4[4];
    #pragma unroll
    for (int j = 0; j < 4; ++j) inv4[j] = invn[nbase + wc * 64 + j * 16 + l15];
    #pragma unroll
    for (int i = 0; i < 4; ++i)
      #pragma unroll
      for (int q = 0; q < 4; ++q) {
        const int iq = i * 4 + q;
        #pragma unroll
        for (int j = 0; j < 4; ++j) {
          const float v = acc[i][j][q] * inv4[j];
          const int k = nbase + wc * 64 + j * 16 + l15;
          if (v > bv[iq]) { b2v[iq] = bv[iq]; bv[iq] = v; bi[iq] = k; }
          else if (v > b2v[iq]) b2v[iq] = v;
        }
      }
  }

  // butterfly merge across the 16 lanes (cols) sharing each row
  #pragma unroll
  for (int m = 1; m < 16; m <<= 1) {
    #pragma unroll
    for (int iq = 0; iq < 16; ++iq) {
      const float ov = __shfl_xor(bv[iq], m);
      const int   oi = __shfl_xor(bi[iq], m);
      const float o2 = __shfl_xor(b2v[iq], m);
      const float n2 = fmaxf(fmaxf(b2v[iq], o2), fminf(bv[iq], ov));
      if (ov > bv[iq] || (ov == bv[iq] && oi < bi[iq])) { bv[iq] = ov; bi[iq] = oi; }
      b2v[iq] = n2;
    }
  }

  // cross-wave (wc) merge via LDS scratch (staging complete; reuse As)
  __builtin_amdgcn_s_barrier();
  float* lv1 = reinterpret_cast<float*>(As[0]);
  float* lv2 = lv1 + 128;
  int*   li1 = reinterpret_cast<int*>(lv2 + 128);
  if (wc == 1 && l15 == 0) {
    #pragma unroll
    for (int i = 0; i < 4; ++i)
      #pragma unroll
      for (int q = 0; q < 4; ++q) {
        const int rl = wr * 64 + i * 16 + kg * 4 + q;
        lv1[rl] = bv[i * 4 + q]; lv2[rl] = b2v[i * 4 + q]; li1[rl] = bi[i * 4 + q];
      }
  }
  __syncthreads();
  if (wc == 0 && l15 == 0) {
    #pragma unroll
    for (int i = 0; i < 4; ++i)
      #pragma unroll
      for (int q = 0; q < 4; ++q) {
        const int iq = i * 4 + q;
        const int rl = wr * 64 + i * 16 + kg * 4 + q;
        const float ov = lv1[rl]; const float o2 = lv2[rl]; const int oi = li1[rl];
        const float n2 = fmaxf(fmaxf(b2v[iq], o2), fminf(bv[iq], ov));
        float v1 = bv[iq]; int i1 = bi[iq];
        if (ov > v1 || (ov == v1 && oi < i1)) { v1 = ov; i1 = oi; }
        const size_t g = (size_t)cg * NROWS + m0 + rl;
        partV1[g] = v1; partI1[g] = i1; partV2[g] = n2;
      }
  }
}

// ---------------- merge colgroups, flag low-margin rows ----------------
__global__ __launch_bounds__(256) void vq_merge_flag_kernel(
    const float* __restrict__ partV1, const int* __restrict__ partI1,
    const float* __restrict__ partV2,
    int* __restrict__ final_idx, int* __restrict__ flag, int* __restrict__ cnt) {
  const int n = blockIdx.x * 256 + threadIdx.x;
  float v1 = partV1[n]; int i1 = partI1[n]; float v2 = partV2[n];
  #pragma unroll
  for (int cg = 1; cg < 8; ++cg) {
    const float pv1 = partV1[(size_t)cg * NROWS + n];
    const int   pi1 = partI1[(size_t)cg * NROWS + n];
    const float pv2 = partV2[(size_t)cg * NROWS + n];
    const float n2 = fmaxf(fmaxf(v2, pv2), fminf(v1, pv1));
    if (pv1 > v1) { v1 = pv1; i1 = pi1; }   // ties keep earlier cg (smaller k)
    v2 = n2;
  }
  final_idx[n] = i1;
  if (v1 - v2 < RESCORE_THRESH) {
    const int p = atomicAdd(cnt, 1);
    flag[p] = n;
  }
}

// ---------------- exact fp32 rescore of flagged rows ----------------
__global__ __launch_bounds__(256) void vq_rescore_kernel(
    const float* __restrict__ z, const float* __restrict__ e,
    const float* __restrict__ invn, const int* __restrict__ cnt,
    const int* __restrict__ flag, int* __restrict__ final_idx) {
  __shared__ float zr[8][256];
  __shared__ int rows[8];
  __shared__ float redv[8][4];
  __shared__ int   redi[8][4];
  const int t = threadIdx.x;
  const int total = *cnt;
  for (int base = blockIdx.x * 8; base < total; base += gridDim.x * 8) {
    const int nr = min(8, total - base);
    __syncthreads();
    if (t < 8) rows[t] = (base + t < total) ? flag[base + t] : flag[base];
    __syncthreads();
    for (int rr = 0; rr < 8; ++rr) {
      if (rr < nr) {
        const int n = rows[rr];
        const int b = n >> 10, hw = n & 1023;
        zr[rr][t] = z[(size_t)b * 262144 + (size_t)t * 1024 + hw];
      } else {
        zr[rr][t] = 0.f;
      }
    }
    __syncthreads();
    float bvv[8]; int bii[8];
    #pragma unroll
    for (int rr = 0; rr < 8; ++rr) { bvv[rr] = -3.4e38f; bii[rr] = 0; }
    for (int jj = 0; jj < 32; ++jj) {
      const int k = t * 32 + jj;
      const float4* er = reinterpret_cast<const float4*>(e + (size_t)k * CDIM);
      float d[8];
      #pragma unroll
      for (int rr = 0; rr < 8; ++rr) d[rr] = 0.f;
      for (int c4 = 0; c4 < 64; ++c4) {
        const float4 ev = er[c4];
        #pragma unroll
        for (int rr = 0; rr < 8; ++rr) {
          d[rr] = fmaf(ev.x, zr[rr][c4 * 4 + 0], d[rr]);
          d[rr] = fmaf(ev.y, zr[rr][c4 * 4 + 1], d[rr]);
          d[rr] = fmaf(ev.z, zr[rr][c4 * 4 + 2], d[rr]);
          d[rr] = fmaf(ev.w, zr[rr][c4 * 4 + 3], d[rr]);
        }
      }
      const float inv = invn[k];
      #pragma unroll
      for (int rr = 0; rr < 8; ++rr) {
        const float v = d[rr] * inv;
        if (v > bvv[rr]) { bvv[rr] = v; bii[rr] = k; }  // ascending k: first kept
      }
    }
    #pragma unroll
    for (int m = 1; m < 64; m <<= 1) {
      #pragma unroll
      for (int rr = 0; rr < 8; ++rr) {
        const float ov = __shfl_xor(bvv[rr], m);
        const int   oi = __shfl_xor(bii[rr], m);
        if (ov > bvv[rr] || (ov == bvv[rr] && oi < bii[rr])) { bvv[rr] = ov; bii[rr] = oi; }
      }
    }
    if ((t & 63) == 0) {
      #pragma unroll
      for (int rr = 0; rr < 8; ++rr) { redv[rr][t >> 6] = bvv[rr]; redi[rr][t >> 6] = bii[rr]; }
    }
    __syncthreads();
    if (t < nr) {
      float v = redv[t][0]; int i = redi[t][0];
      #pragma unroll
      for (int ww = 1; ww < 4; ++ww) {
        if (redv[t][ww] > v || (redv[t][ww] == v && redi[t][ww] < i)) { v = redv[t][ww]; i = redi[t][ww]; }
      }
      final_idx[rows[t]] = i;
    }
  }
}

// ---------------- gather + out write + loss partial (reads final_idx) ----------------
__global__ __launch_bounds__(256) void vq_gather_loss2_kernel(
    const float* __restrict__ z, const float* __restrict__ e,
    const int* __restrict__ final_idx,
    float* __restrict__ out, float* __restrict__ lossacc) {
  __shared__ int sidx[64];
  const int t  = threadIdx.x;
  const int n0 = blockIdx.x * 64;
  if (t < 64) {
    const int id = final_idx[n0 + t];
    sidx[t] = id;
    out[OUT_ELEMS + 1 + n0 + t] = (float)id;
  }
  __syncthreads();
  const int b    = n0 >> 10;
  const int hw0  = n0 & 1023;
  const int nsub = t & 63;
  const int cg   = t >> 6;
  const float* erow = e + (size_t)sidx[nsub] * CDIM;
  float lsum = 0.f;
  for (int c = cg; c < CDIM; c += 4) {
    const float  v   = erow[c];
    const size_t off = (size_t)b * (CDIM * HWPB) + (size_t)c * HWPB + hw0 + nsub;
    const float  d   = v - z[off];
    lsum += d * d;
    out[off] = v;
  }
  #pragma unroll
  for (int o = 32; o > 0; o >>= 1) lsum += __shfl_down(lsum, o);
  __shared__ float wsum[4];
  if ((t & 63) == 0) wsum[t >> 6] = lsum;
  __syncthreads();
  if (t == 0) atomicAdd(lossacc, wsum[0] + wsum[1] + wsum[2] + wsum[3]);
}

__global__ void vq_finalize_kernel(const float* __restrict__ lossacc,
                                   float* __restrict__ out) {
  out[OUT_ELEMS] = 1.25f * lossacc[0] / (float)OUT_ELEMS;
}

// ================= fallback fp32 path (round-3, proven) =================
#define BM 128
#define BN 128
#define KC 16
#define KSPLIT 4

__global__ __launch_bounds__(256) void vq_dist_argmax_kernel(
    const float* __restrict__ z, const float* __restrict__ e,
    const float* __restrict__ invn,
    float* __restrict__ bestval, int* __restrict__ bestidx) {
  __shared__ float as[KC][BM];
  __shared__ float bs[KC][BN + 4];
  const int t  = threadIdx.x;
  const int tx = t & 15;
  const int ty = t >> 4;
  const int n0 = blockIdx.x * BM;
  const int b   = n0 >> 10;
  const int hw0 = n0 & 1023;
  const float* zbase = z + (size_t)b * (CDIM * HWPB) + hw0;
  const int kbeg = blockIdx.y * (KCODES / KSPLIT);
  float bv[8]; int bi[8];
  #pragma unroll
  for (int i = 0; i < 8; ++i) { bv[i] = -3.4e38f; bi[i] = 0; }
  const int a_lm4 = (t & 31) * 4;
  const int a_cc  = t >> 5;
  const int b_kk  = t >> 2;
  const int b_q4  = (t & 3) * 4;
  for (int kt = 0; kt < (KCODES / KSPLIT) / BN; ++kt) {
    const int k0 = kbeg + kt * BN;
    float acc[8][8];
    #pragma unroll
    for (int i = 0; i < 8; ++i)
      #pragma unroll
      for (int j = 0; j < 8; ++j) acc[i][j] = 0.f;
    for (int c0 = 0; c0 < CDIM; c0 += KC) {
      #pragma unroll
      for (int p = 0; p < 2; ++p) {
        const int cc = a_cc + 8 * p;
        const float4 v = *reinterpret_cast<const float4*>(
            zbase + (size_t)(c0 + cc) * HWPB + a_lm4);
        *reinterpret_cast<float4*>(&as[cc][a_lm4]) = v;
      }
      #pragma unroll
      for (int p = 0; p < 2; ++p) {
        const int kk = b_kk + 64 * p;
        const float4 v = *reinterpret_cast<const float4*>(
            e + (size_t)(k0 + kk) * CDIM + c0 + b_q4);
        bs[b_q4 + 0][kk] = v.x;
        bs[b_q4 + 1][kk] = v.y;
        bs[b_q4 + 2][kk] = v.z;
        bs[b_q4 + 3][kk] = v.w;
      }
      __syncthreads();
      #pragma unroll
      for (int cc = 0; cc < KC; ++cc) {
        const float4 a0 = *reinterpret_cast<const float4*>(&as[cc][ty * 8]);
        const float4 a1 = *reinterpret_cast<const float4*>(&as[cc][ty * 8 + 4]);
        const float4 b0 = *reinterpret_cast<const float4*>(&bs[cc][tx * 4]);
        const float4 b1 = *reinterpret_cast<const float4*>(&bs[cc][64 + tx * 4]);
        const float a[8]  = {a0.x, a0.y, a0.z, a0.w, a1.x, a1.y, a1.z, a1.w};
        const float bb[8] = {b0.x, b0.y, b0.z, b0.w, b1.x, b1.y, b1.z, b1.w};
        #pragma unroll
        for (int i = 0; i < 8; ++i)
          #pragma unroll
          for (int j = 0; j < 8; ++j)
            acc[i][j] = fmaf(a[i], bb[j], acc[i][j]);
      }
      __syncthreads();
    }
    #pragma unroll
    for (int j = 0; j < 8; ++j) {
      const int k = k0 + ((j < 4) ? (tx * 4 + j) : (64 + tx * 4 + (j - 4)));
      const float inv = invn[k];
      #pragma unroll
      for (int i = 0; i < 8; ++i) {
        const float v = acc[i][j] * inv;
        if (v > bv[i]) { bv[i] = v; bi[i] = k; }
      }
    }
  }
  #pragma unroll
  for (int m = 1; m < 16; m <<= 1) {
    #pragma unroll
    for (int i = 0; i < 8; ++i) {
      const float vo = __shfl_xor(bv[i], m);
      const int   io = __shfl_xor(bi[i], m);
      if (vo > bv[i] || (vo == bv[i] && io < bi[i])) { bv[i] = vo; bi[i] = io; }
    }
  }
  if (tx == 0) {
    #pragma unroll
    for (int i = 0; i < 8; ++i) {
      bestval[blockIdx.y * NROWS + n0 + ty * 8 + i] = bv[i];
      bestidx[blockIdx.y * NROWS + n0 + ty * 8 + i] = bi[i];
    }
  }
}

__global__ __launch_bounds__(256) void vq_gather_loss_kernel(
    const float* __restrict__ z, const float* __restrict__ e,
    const float* __restrict__ bestval, const int* __restrict__ bestidx,
    float* __restrict__ out, float* __restrict__ lossacc) {
  __shared__ int sidx[64];
  const int t  = threadIdx.x;
  const int n0 = blockIdx.x * 64;
  if (t < 64) {
    const int n = n0 + t;
    float best = bestval[n];
    int   bid  = bestidx[n];
    #pragma unroll
    for (int p = 1; p < KSPLIT; ++p) {
      const float v = bestval[p * NROWS + n];
      const int  id = bestidx[p * NROWS + n];
      if (v > best) { best = v; bid = id; }
    }
    sidx[t] = bid;
    out[OUT_ELEMS + 1 + n] = (float)bid;
  }
  __syncthreads();
  const int b    = n0 >> 10;
  const int hw0  = n0 & 1023;
  const int nsub = t & 63;
  const int cg   = t >> 6;
  const float* erow = e + (size_t)sidx[nsub] * CDIM;
  float lsum = 0.f;
  for (int c = cg; c < CDIM; c += 4) {
    const float  v   = erow[c];
    const size_t off = (size_t)b * (CDIM * HWPB) + (size_t)c * HWPB + hw0 + nsub;
    const float  d   = v - z[off];
    lsum += d * d;
    out[off] = v;
  }
  #pragma unroll
  for (int o = 32; o > 0; o >>= 1) lsum += __shfl_down(lsum, o);
  __shared__ float wsum[4];
  if ((t & 63) == 0) wsum[t >> 6] = lsum;
  __syncthreads();
  if (t == 0) atomicAdd(lossacc, wsum[0] + wsum[1] + wsum[2] + wsum[3]);
}

// ================================ launch ================================
extern "C" void kernel_launch(void* const* d_in, const int* in_sizes, int n_in,
                              void* d_out, int out_size, void* d_ws, size_t ws_size,
                              hipStream_t stream) {
  const float* z = (const float*)d_in[0];        // [32,256,32,32]
  const float* e = (const float*)d_in[1];        // [8192,256]
  float* out = (float*)d_out;

  const size_t szA2 = (size_t)NROWS * 512 * 2;       // 33,554,432
  const size_t szB2 = (size_t)KCODES * 512 * 2;      //  8,388,608
  const size_t szInv = KCODES * 4;
  const size_t szPart = (size_t)8 * NROWS * 4;
  const size_t need = szA2 + szB2 + szInv + 3 * szPart + 2 * (size_t)NROWS * 4 + 256;

  if (ws_size >= need) {
    char* p = (char*)d_ws;
    ushort_t* A2 = (ushort_t*)p;       p += szA2;
    ushort_t* B2 = (ushort_t*)p;       p += szB2;
    float* invn  = (float*)p;          p += szInv;
    float* partV1 = (float*)p;         p += szPart;
    float* partV2 = (float*)p;         p += szPart;
    int*   partI1 = (int*)p;           p += szPart;
    int*   final_idx = (int*)p;        p += (size_t)NROWS * 4;
    int*   flag = (int*)p;             p += (size_t)NROWS * 4;
    int*   cnt = (int*)p;
    float* lossacc = (float*)(cnt + 1);

    hipMemsetAsync(cnt, 0, 8, stream);  // cnt + lossacc
    vq_prep_b_kernel<<<KCODES / 4, 256, 0, stream>>>(e, B2, invn);
    vq_prep_a_kernel<<<2048, 256, 0, stream>>>(z, A2);
    dim3 grid(NROWS / 128, 8);
    vq_mfma_kernel<<<grid, 256, 0, stream>>>(A2, B2, invn, partV1, partI1, partV2);
    vq_merge_flag_kernel<<<NROWS / 256, 256, 0, stream>>>(partV1, partI1, partV2,
                                                          final_idx, flag, cnt);
    vq_rescore_kernel<<<256, 256, 0, stream>>>(z, e, invn, cnt, flag, final_idx);
    vq_gather_loss2_kernel<<<NROWS / 64, 256, 0, stream>>>(z, e, final_idx, out, lossacc);
    vq_finalize_kernel<<<1, 1, 0, stream>>>(lossacc, out);
  } else {
    // fallback: proven fp32 path (round 3)
    float* invn    = (float*)d_ws;
    float* bestval = invn + KCODES;
    int*   bestidx = (int*)(bestval + KSPLIT * NROWS);
    float* lossacc = (float*)(bestidx + KSPLIT * NROWS);
    hipMemsetAsync(lossacc, 0, sizeof(float), stream);
    vq_invnorm_kernel<<<KCODES / 4, 256, 0, stream>>>(e, invn);
    dim3 grid(NROWS / BM, KSPLIT);
    vq_dist_argmax_kernel<<<grid, 256, 0, stream>>>(z, e, invn, bestval, bestidx);
    vq_gather_loss_kernel<<<NROWS / 64, 256, 0, stream>>>(z, e, bestval, bestidx,
                                                          out, lossacc);
    vq_finalize_kernel<<<1, 1, 0, stream>>>(lossacc, out);
  }
}